// Round 7
// baseline (203.199 us; speedup 1.0000x reference)
//
#include <hip/hip_runtime.h>

#define T 4096
#define D 66
#define NL 3
#define NC 64          // scan chunks per modality
#define JC 64          // T / NC
#define HS 36          // ht row stride (32 rows + pad, multiple of 4 for b128)
#define WS 68          // W LDS col stride (multiple of 4 for b128)
#define DD (D * D)     // 4356
#define NBLK 320
#define NTHR 256
#define UNIT_F (2 * D * HS + D * WS)   // 9240 floats per MLP unit

// ---------------------------------------------------------------------------
// Device-scope grid barrier (single-use counter, zeroed by host memset before
// launch). Capacity proof: LDS 73,920 B/block -> 2 blocks/CU (160 KiB LDS),
// 256 CU * 2 = 512 >= 320 blocks, so all blocks are co-resident and the spin
// cannot deadlock. Agent-scope release/acquire orders the phase handoffs
// across per-XCD L2s.
// ---------------------------------------------------------------------------
__device__ __forceinline__ void grid_barrier(int* cnt) {
    __syncthreads();
    if (threadIdx.x == 0) {
        __threadfence();   // release prior writes device-wide
        __hip_atomic_fetch_add(cnt, 1, __ATOMIC_ACQ_REL, __HIP_MEMORY_SCOPE_AGENT);
        while (__hip_atomic_load(cnt, __ATOMIC_ACQUIRE, __HIP_MEMORY_SCOPE_AGENT) < NBLK)
            __builtin_amdgcn_s_sleep(1);
        __threadfence();   // acquire other blocks' writes
    }
    __syncthreads();
}

// ---------------------------------------------------------------------------
// One persistent kernel, 4 phases separated by grid_barrier():
//  P1 MLP: 640 2-wave units (5 jobs x 128 tiles of 32 rows), 2 units/block.
//     Register-tiled 4x4 outer product, weights prefetched one layer ahead,
//     activations transposed in LDS (unit u owns smem[u]).
//  P2 scan: blocks 0..255 = (m, chunk); thread c<132 owns state column c,
//     serial over JC rows, coalesced 528 B row stores; threads 144..207
//     extract the timestamp column into compact TM.
//  P3 chunk-offset: 528 wave-units (m, c); lane=chunk, shuffle scan.
//  P4 out: 1280 waves x 3-4 rows; 2-round ballot search (round 1 on an LDS
//     segment-end table), lane-parallel 132-float dot, shuffle reduce.
// ---------------------------------------------------------------------------
__global__ __launch_bounds__(NTHR) void fused_kernel(
    const float* __restrict__ x1, const float* __restrict__ x2,
    const float* __restrict__ x3, const float* __restrict__ x4,
    const float* __restrict__ wq, const float* __restrict__ bq,
    const float* __restrict__ wk, const float* __restrict__ bk,
    float* __restrict__ Q, float* __restrict__ Kp,
    float* __restrict__ S, float* __restrict__ chunkSum,
    float* __restrict__ chunkOff, float* __restrict__ TM,
    int* __restrict__ bar, float* __restrict__ out)
{
    __shared__ float smem[2][UNIT_F];

    // ================= Phase 1: MLP =================
    {
        const int u    = threadIdx.x >> 7;       // unit slot 0/1
        const int t    = threadIdx.x & 127;
        const int unit = blockIdx.x * 2 + u;     // 0..639
        const int job  = unit >> 7;              // 0: Q; 1..4: K_{job-1}
        const int tile = unit & 127;             // 32-row tile
        const float* X = (job <= 1) ? x1 : (job == 2 ? x2 : (job == 3 ? x3 : x4));
        const float* W = (job == 0) ? wq : wk;
        const float* Bs = (job == 0) ? bq : bk;
        float* ht = smem[u];                     // [2][D*HS]
        float* Wl = smem[u] + 2 * D * HS;        // [D*WS]

        // stage x tile transposed: ht[0][d*HS + r]
        const float* xt = X + (size_t)tile * 32 * D;
#pragma unroll 4
        for (int k = t; k < 32 * D; k += 128) {
            const int r = k / D;
            const int d = k - r * D;
            ht[d * HS + r] = xt[k];
        }

        // prefetch layer-0 weights into registers
        float wreg[35];
#pragma unroll
        for (int i = 0; i < 35; ++i) {
            const int k = t + i * 128;
            if (k < DD) wreg[i] = W[k];
        }

        const int lane = t & 63;
        const int wv   = t >> 6;
        const int og   = lane & 15;
        const int rg   = lane >> 4;
        const int r0   = wv * 16 + rg * 4;
        const int c0   = og * 4;

        int src = 0;
#pragma unroll 1
        for (int l = 0; l < NL; ++l) {
#pragma unroll
            for (int i = 0; i < 35; ++i) {
                const int k = t + i * 128;
                if (k < DD) {
                    const int d = k / D;
                    const int o = k - d * D;
                    Wl[d * WS + o] = wreg[i];
                }
            }
            __syncthreads();

            if (l < NL - 1) {
                const float* Wg = W + (l + 1) * DD;
#pragma unroll
                for (int i = 0; i < 35; ++i) {
                    const int k = t + i * 128;
                    if (k < DD) wreg[i] = Wg[k];
                }
            }

            float acc[4][4];
            float acce[4];
            {
                const float b0 = Bs[l * D + c0 + 0];
                const float b1 = Bs[l * D + c0 + 1];
                const float b2 = Bs[l * D + c0 + 2];
                const float b3 = Bs[l * D + c0 + 3];
                const float be = Bs[l * D + 64 + (og & 1)];
#pragma unroll
                for (int ri = 0; ri < 4; ++ri) {
                    acc[ri][0] = b0; acc[ri][1] = b1;
                    acc[ri][2] = b2; acc[ri][3] = b3;
                    acce[ri] = be;
                }
            }

            const float* hs = ht + src * (D * HS);
#pragma unroll 6
            for (int d = 0; d < D; ++d) {
                const float4 h4 = *(const float4*)&hs[d * HS + r0];
                const float4 w4 = *(const float4*)&Wl[d * WS + c0];
                const float we  = Wl[d * WS + 64 + (og & 1)];
                const float hv[4] = {h4.x, h4.y, h4.z, h4.w};
#pragma unroll
                for (int ri = 0; ri < 4; ++ri) {
                    acc[ri][0] = fmaf(hv[ri], w4.x, acc[ri][0]);
                    acc[ri][1] = fmaf(hv[ri], w4.y, acc[ri][1]);
                    acc[ri][2] = fmaf(hv[ri], w4.z, acc[ri][2]);
                    acc[ri][3] = fmaf(hv[ri], w4.w, acc[ri][3]);
                    acce[ri]   = fmaf(hv[ri], we,  acce[ri]);
                }
            }

            if (l < NL - 1) {
                const int nb = 1 - src;
                float* hn = ht + nb * (D * HS);
#pragma unroll
                for (int ri = 0; ri < 4; ++ri) {
#pragma unroll
                    for (int ci = 0; ci < 4; ++ci)
                        hn[(c0 + ci) * HS + r0 + ri] = fmaxf(acc[ri][ci], 0.0f);
                    if (og < 2)
                        hn[(64 + og) * HS + r0 + ri] = fmaxf(acce[ri], 0.0f);
                }
                __syncthreads();
                src = nb;
            } else {
                float* outp = (job == 0) ? Q : (Kp + (size_t)(job - 1) * T * D);
#pragma unroll
                for (int ri = 0; ri < 4; ++ri) {
                    const int row = tile * 32 + r0 + ri;
                    float* rp = outp + (size_t)row * D + c0;
                    *(float2*)rp       = make_float2(acc[ri][0], acc[ri][1]);
                    *((float2*)rp + 1) = make_float2(acc[ri][2], acc[ri][3]);
                    if (og < 2) outp[(size_t)row * D + 64 + og] = acce[ri];
                }
            }
        }
    }

    grid_barrier(bar + 0);

    // ================= Phase 2: in-chunk scan + TM extract =================
    if (blockIdx.x < NC * 4) {
        const int ch = blockIdx.x & 63;
        const int m  = blockIdx.x >> 6;
        const int c  = threadIdx.x;
        const float* Xm = (m == 0) ? x1 : (m == 1 ? x2 : (m == 2 ? x3 : x4));
        const int j0 = ch * JC;

        if (c >= 144 && c < 144 + JC) {
            const int j = j0 + (c - 144);
            TM[m * T + j] = Xm[(size_t)j * D + (D - 1)];
        }
        if (c < 132) {
            const float* Km = Kp + (size_t)m * T * D;
            const int d = c >> 1;
            const int v = c & 1;
            float run = 0.0f;
#pragma unroll 8
            for (int jj = 0; jj < JC; ++jj) {
                const int j = j0 + jj;
                run = fmaf(Km[(size_t)j * D + d], Xm[(size_t)j * D + v], run);
                S[((size_t)m * T + j) * 132 + c] = run;
            }
            chunkSum[((size_t)m * NC + ch) * 132 + c] = run;
        }
    }

    grid_barrier(bar + 1);

    // ================= Phase 3: chunk-offset shuffle scan =================
    {
        const int wv   = threadIdx.x >> 6;
        const int lane = threadIdx.x & 63;           // chunk index (NC == 64)
        const int gw   = blockIdx.x * 4 + wv;        // 0..1279
        const int m    = gw & 3;
        const int c    = gw >> 2;
        if (c < 132) {
            const float v = chunkSum[((size_t)m * NC + lane) * 132 + c];
            float inc = v;
#pragma unroll
            for (int off = 1; off < 64; off <<= 1) {
                const float y = __shfl_up(inc, off);
                if (lane >= off) inc += y;
            }
            chunkOff[((size_t)m * NC + lane) * 132 + c] = inc - v;
        }
    }

    grid_barrier(bar + 2);

    // ================= Phase 4: gather + dot =================
    {
        float* segEnd = smem[0];                     // 4*64 floats, reuse LDS
        const int wv   = threadIdx.x >> 6;
        const int lane = threadIdx.x & 63;
        segEnd[wv * 64 + lane] = TM[wv * T + lane * 64 + 63];
        __syncthreads();

        for (int i = blockIdx.x * 4 + wv; i < T; i += NBLK * 4) {
            const float t1i = TM[i];                 // modality 0 times == t1
            const float q0  = Q[(size_t)i * D + lane];
            const float q1  = (lane < 2) ? Q[(size_t)i * D + 64 + lane] : 0.0f;
            float acc0 = 0.0f, acc1 = 0.0f;

            int seg[4];
#pragma unroll
            for (int m = 0; m < 4; ++m) {
                const unsigned long long b = __ballot(segEnd[m * 64 + lane] <= t1i);
                const int hi = __popcll(b);
                seg[m] = (hi < 63) ? hi : 63;
            }
            int idx[4];
#pragma unroll
            for (int m = 0; m < 4; ++m) {
                const float sv = TM[m * T + seg[m] * 64 + lane];
                const unsigned long long b = __ballot(sv <= t1i);
                idx[m] = seg[m] * 64 + __popcll(b) - 1;   // pos-1; -1 => none
            }

#pragma unroll
            for (int m = 0; m < 4; ++m) {
                if (idx[m] >= 0) {
                    const float* sp = S + ((size_t)m * T + idx[m]) * 132;
                    const float* op = chunkOff + ((size_t)m * NC + (idx[m] / JC)) * 132;
                    const float2 s0 = *(const float2*)(sp + lane * 2);
                    const float2 c0 = *(const float2*)(op + lane * 2);
                    acc0 = fmaf(q0, s0.x + c0.x, acc0);
                    acc1 = fmaf(q0, s0.y + c0.y, acc1);
                    if (lane < 2) {
                        const float2 s1 = *(const float2*)(sp + 128 + lane * 2);
                        const float2 c1 = *(const float2*)(op + 128 + lane * 2);
                        acc0 = fmaf(q1, s1.x + c1.x, acc0);
                        acc1 = fmaf(q1, s1.y + c1.y, acc1);
                    }
                }
            }

#pragma unroll
            for (int off = 32; off >= 1; off >>= 1) {
                acc0 += __shfl_down(acc0, off);
                acc1 += __shfl_down(acc1, off);
            }
            if (lane == 0) {
                out[(size_t)i * 2 + 0] = acc0;
                out[(size_t)i * 2 + 1] = acc1;
            }
        }
    }
}

extern "C" void kernel_launch(void* const* d_in, const int* in_sizes, int n_in,
                              void* d_out, int out_size, void* d_ws, size_t ws_size,
                              hipStream_t stream)
{
    (void)in_sizes; (void)n_in; (void)out_size; (void)ws_size;
    const float* x1 = (const float*)d_in[0];
    const float* x2 = (const float*)d_in[1];
    const float* x3 = (const float*)d_in[2];
    const float* x4 = (const float*)d_in[3];
    const float* wq = (const float*)d_in[4];
    const float* bq = (const float*)d_in[5];
    const float* wk = (const float*)d_in[6];
    const float* bk = (const float*)d_in[7];

    float* ws = (float*)d_ws;
    float* Q        = ws;                  // 4096*66            = 270336
    float* Kp       = ws + 270336;         // 4*4096*66          = 1081344
    float* S        = ws + 1351680;        // 4*4096*132         = 2162688
    float* chunkSum = ws + 3514368;        // 4*NC*132           = 33792
    float* chunkOff = ws + 3548160;        // 4*NC*132           = 33792
    float* TM       = ws + 3581952;        // 4*4096             = 16384
    int*   bar      = (int*)(ws + 3598336);// 3 ints (barrier counters)

    // zero the single-use barrier counters (graph-capturable async memset)
    hipMemsetAsync(bar, 0, 3 * sizeof(int), stream);

    fused_kernel<<<NBLK, NTHR, 0, stream>>>(x1, x2, x3, x4, wq, bq, wk, bk,
                                            Q, Kp, S, chunkSum, chunkOff, TM,
                                            bar, (float*)d_out);
}

// Round 8
// 122.414 us; speedup vs baseline: 1.6599x; 1.6599x over previous
//
#include <hip/hip_runtime.h>

#define T 4096
#define D 66
#define NL 3
#define NC 64          // scan chunks per modality
#define JC 64          // T / NC
#define HS 36          // ht row stride (32 rows + pad, multiple of 4 for b128)
#define WS 68          // W LDS col stride (multiple of 4 for b128)
#define DD (D * D)     // 4356
#define NBLK 320
#define NTHR 256
#define UNIT_F (2 * D * HS + D * WS)   // 9240 floats per MLP unit

// ---------------------------------------------------------------------------
// Device-scope grid barrier (single-use counter, zeroed by host memset before
// launch). Capacity proof: LDS 74,240 B/block -> 2 blocks/CU (160 KiB LDS),
// 256 CU * 2 = 512 >= 320 blocks: all blocks co-resident, spin cannot
// deadlock (occupancy counter R7 confirmed residency).
// CRITICAL: the spin uses RELAXED loads (plain coherent load, no cache
// invalidate). R7's ACQUIRE-in-loop emitted buffer_inv per poll -> 203 us.
// One release (on the add) + one acquire fence (after exit) order the
// phase handoffs across per-XCD L2s.
// ---------------------------------------------------------------------------
__device__ __forceinline__ void grid_barrier(int* cnt) {
    __syncthreads();
    if (threadIdx.x == 0) {
        __hip_atomic_fetch_add(cnt, 1, __ATOMIC_RELEASE, __HIP_MEMORY_SCOPE_AGENT);
        while (__hip_atomic_load(cnt, __ATOMIC_RELAXED, __HIP_MEMORY_SCOPE_AGENT) < NBLK)
            __builtin_amdgcn_s_sleep(2);
        __builtin_amdgcn_fence(__ATOMIC_ACQUIRE, "agent");
    }
    __syncthreads();
}

// ---------------------------------------------------------------------------
// One persistent kernel, 4 phases separated by grid_barrier():
//  P1 MLP: 640 2-wave units (5 jobs x 128 tiles of 32 rows), 2 units/block.
//  P2 scan: blocks 0..255 = (m, chunk); thread c<132 owns state column c.
//  P3 chunk-offset: 528 wave-units (m, c); lane=chunk, shuffle scan.
//  P4 out: 1280 waves x 3-4 rows; 2-round ballot search + 132-float dot.
// ---------------------------------------------------------------------------
__global__ __launch_bounds__(NTHR) void fused_kernel(
    const float* __restrict__ x1, const float* __restrict__ x2,
    const float* __restrict__ x3, const float* __restrict__ x4,
    const float* __restrict__ wq, const float* __restrict__ bq,
    const float* __restrict__ wk, const float* __restrict__ bk,
    float* __restrict__ Q, float* __restrict__ Kp,
    float* __restrict__ S, float* __restrict__ chunkSum,
    float* __restrict__ chunkOff, float* __restrict__ TM,
    int* __restrict__ bar, float* __restrict__ out)
{
    __shared__ float smem[2][UNIT_F];

    // ================= Phase 1: MLP =================
    {
        const int u    = threadIdx.x >> 7;       // unit slot 0/1
        const int t    = threadIdx.x & 127;
        const int unit = blockIdx.x * 2 + u;     // 0..639
        const int job  = unit >> 7;              // 0: Q; 1..4: K_{job-1}
        const int tile = unit & 127;             // 32-row tile
        const float* X = (job <= 1) ? x1 : (job == 2 ? x2 : (job == 3 ? x3 : x4));
        const float* W = (job == 0) ? wq : wk;
        const float* Bs = (job == 0) ? bq : bk;
        float* ht = smem[u];                     // [2][D*HS]
        float* Wl = smem[u] + 2 * D * HS;        // [D*WS]

        // stage x tile transposed: ht[0][d*HS + r]
        const float* xt = X + (size_t)tile * 32 * D;
#pragma unroll 4
        for (int k = t; k < 32 * D; k += 128) {
            const int r = k / D;
            const int d = k - r * D;
            ht[d * HS + r] = xt[k];
        }

        // prefetch layer-0 weights into registers
        float wreg[35];
#pragma unroll
        for (int i = 0; i < 35; ++i) {
            const int k = t + i * 128;
            if (k < DD) wreg[i] = W[k];
        }

        const int lane = t & 63;
        const int wv   = t >> 6;
        const int og   = lane & 15;
        const int rg   = lane >> 4;
        const int r0   = wv * 16 + rg * 4;
        const int c0   = og * 4;

        int src = 0;
#pragma unroll 1
        for (int l = 0; l < NL; ++l) {
#pragma unroll
            for (int i = 0; i < 35; ++i) {
                const int k = t + i * 128;
                if (k < DD) {
                    const int d = k / D;
                    const int o = k - d * D;
                    Wl[d * WS + o] = wreg[i];
                }
            }
            __syncthreads();

            if (l < NL - 1) {
                const float* Wg = W + (l + 1) * DD;
#pragma unroll
                for (int i = 0; i < 35; ++i) {
                    const int k = t + i * 128;
                    if (k < DD) wreg[i] = Wg[k];
                }
            }

            float acc[4][4];
            float acce[4];
            {
                const float b0 = Bs[l * D + c0 + 0];
                const float b1 = Bs[l * D + c0 + 1];
                const float b2 = Bs[l * D + c0 + 2];
                const float b3 = Bs[l * D + c0 + 3];
                const float be = Bs[l * D + 64 + (og & 1)];
#pragma unroll
                for (int ri = 0; ri < 4; ++ri) {
                    acc[ri][0] = b0; acc[ri][1] = b1;
                    acc[ri][2] = b2; acc[ri][3] = b3;
                    acce[ri] = be;
                }
            }

            const float* hs = ht + src * (D * HS);
#pragma unroll 6
            for (int d = 0; d < D; ++d) {
                const float4 h4 = *(const float4*)&hs[d * HS + r0];
                const float4 w4 = *(const float4*)&Wl[d * WS + c0];
                const float we  = Wl[d * WS + 64 + (og & 1)];
                const float hv[4] = {h4.x, h4.y, h4.z, h4.w};
#pragma unroll
                for (int ri = 0; ri < 4; ++ri) {
                    acc[ri][0] = fmaf(hv[ri], w4.x, acc[ri][0]);
                    acc[ri][1] = fmaf(hv[ri], w4.y, acc[ri][1]);
                    acc[ri][2] = fmaf(hv[ri], w4.z, acc[ri][2]);
                    acc[ri][3] = fmaf(hv[ri], w4.w, acc[ri][3]);
                    acce[ri]   = fmaf(hv[ri], we,  acce[ri]);
                }
            }

            if (l < NL - 1) {
                const int nb = 1 - src;
                float* hn = ht + nb * (D * HS);
#pragma unroll
                for (int ri = 0; ri < 4; ++ri) {
#pragma unroll
                    for (int ci = 0; ci < 4; ++ci)
                        hn[(c0 + ci) * HS + r0 + ri] = fmaxf(acc[ri][ci], 0.0f);
                    if (og < 2)
                        hn[(64 + og) * HS + r0 + ri] = fmaxf(acce[ri], 0.0f);
                }
                __syncthreads();
                src = nb;
            } else {
                float* outp = (job == 0) ? Q : (Kp + (size_t)(job - 1) * T * D);
#pragma unroll
                for (int ri = 0; ri < 4; ++ri) {
                    const int row = tile * 32 + r0 + ri;
                    float* rp = outp + (size_t)row * D + c0;
                    *(float2*)rp       = make_float2(acc[ri][0], acc[ri][1]);
                    *((float2*)rp + 1) = make_float2(acc[ri][2], acc[ri][3]);
                    if (og < 2) outp[(size_t)row * D + 64 + og] = acce[ri];
                }
            }
        }
    }

    grid_barrier(bar + 0);

    // ================= Phase 2: in-chunk scan + TM extract =================
    if (blockIdx.x < NC * 4) {
        const int ch = blockIdx.x & 63;
        const int m  = blockIdx.x >> 6;
        const int c  = threadIdx.x;
        const float* Xm = (m == 0) ? x1 : (m == 1 ? x2 : (m == 2 ? x3 : x4));
        const int j0 = ch * JC;

        if (c >= 144 && c < 144 + JC) {
            const int j = j0 + (c - 144);
            TM[m * T + j] = Xm[(size_t)j * D + (D - 1)];
        }
        if (c < 132) {
            const float* Km = Kp + (size_t)m * T * D;
            const int d = c >> 1;
            const int v = c & 1;
            float run = 0.0f;
#pragma unroll 8
            for (int jj = 0; jj < JC; ++jj) {
                const int j = j0 + jj;
                run = fmaf(Km[(size_t)j * D + d], Xm[(size_t)j * D + v], run);
                S[((size_t)m * T + j) * 132 + c] = run;
            }
            chunkSum[((size_t)m * NC + ch) * 132 + c] = run;
        }
    }

    grid_barrier(bar + 1);

    // ================= Phase 3: chunk-offset shuffle scan =================
    {
        const int wv   = threadIdx.x >> 6;
        const int lane = threadIdx.x & 63;           // chunk index (NC == 64)
        const int gw   = blockIdx.x * 4 + wv;        // 0..1279
        const int m    = gw & 3;
        const int c    = gw >> 2;
        if (c < 132) {
            const float v = chunkSum[((size_t)m * NC + lane) * 132 + c];
            float inc = v;
#pragma unroll
            for (int off = 1; off < 64; off <<= 1) {
                const float y = __shfl_up(inc, off);
                if (lane >= off) inc += y;
            }
            chunkOff[((size_t)m * NC + lane) * 132 + c] = inc - v;
        }
    }

    grid_barrier(bar + 2);

    // ================= Phase 4: gather + dot =================
    {
        float* segEnd = smem[0];                     // 4*64 floats, reuse LDS
        const int wv   = threadIdx.x >> 6;
        const int lane = threadIdx.x & 63;
        segEnd[wv * 64 + lane] = TM[wv * T + lane * 64 + 63];
        __syncthreads();

        for (int i = blockIdx.x * 4 + wv; i < T; i += NBLK * 4) {
            const float t1i = TM[i];                 // modality 0 times == t1
            const float q0  = Q[(size_t)i * D + lane];
            const float q1  = (lane < 2) ? Q[(size_t)i * D + 64 + lane] : 0.0f;
            float acc0 = 0.0f, acc1 = 0.0f;

            int seg[4];
#pragma unroll
            for (int m = 0; m < 4; ++m) {
                const unsigned long long b = __ballot(segEnd[m * 64 + lane] <= t1i);
                const int hi = __popcll(b);
                seg[m] = (hi < 63) ? hi : 63;
            }
            int idx[4];
#pragma unroll
            for (int m = 0; m < 4; ++m) {
                const float sv = TM[m * T + seg[m] * 64 + lane];
                const unsigned long long b = __ballot(sv <= t1i);
                idx[m] = seg[m] * 64 + __popcll(b) - 1;   // pos-1; -1 => none
            }

#pragma unroll
            for (int m = 0; m < 4; ++m) {
                if (idx[m] >= 0) {
                    const float* sp = S + ((size_t)m * T + idx[m]) * 132;
                    const float* op = chunkOff + ((size_t)m * NC + (idx[m] / JC)) * 132;
                    const float2 s0 = *(const float2*)(sp + lane * 2);
                    const float2 c0 = *(const float2*)(op + lane * 2);
                    acc0 = fmaf(q0, s0.x + c0.x, acc0);
                    acc1 = fmaf(q0, s0.y + c0.y, acc1);
                    if (lane < 2) {
                        const float2 s1 = *(const float2*)(sp + 128 + lane * 2);
                        const float2 c1 = *(const float2*)(op + 128 + lane * 2);
                        acc0 = fmaf(q1, s1.x + c1.x, acc0);
                        acc1 = fmaf(q1, s1.y + c1.y, acc1);
                    }
                }
            }

#pragma unroll
            for (int off = 32; off >= 1; off >>= 1) {
                acc0 += __shfl_down(acc0, off);
                acc1 += __shfl_down(acc1, off);
            }
            if (lane == 0) {
                out[(size_t)i * 2 + 0] = acc0;
                out[(size_t)i * 2 + 1] = acc1;
            }
        }
    }
}

extern "C" void kernel_launch(void* const* d_in, const int* in_sizes, int n_in,
                              void* d_out, int out_size, void* d_ws, size_t ws_size,
                              hipStream_t stream)
{
    (void)in_sizes; (void)n_in; (void)out_size; (void)ws_size;
    const float* x1 = (const float*)d_in[0];
    const float* x2 = (const float*)d_in[1];
    const float* x3 = (const float*)d_in[2];
    const float* x4 = (const float*)d_in[3];
    const float* wq = (const float*)d_in[4];
    const float* bq = (const float*)d_in[5];
    const float* wk = (const float*)d_in[6];
    const float* bk = (const float*)d_in[7];

    float* ws = (float*)d_ws;
    float* Q        = ws;                  // 4096*66            = 270336
    float* Kp       = ws + 270336;         // 4*4096*66          = 1081344
    float* S        = ws + 1351680;        // 4*4096*132         = 2162688
    float* chunkSum = ws + 3514368;        // 4*NC*132           = 33792
    float* chunkOff = ws + 3548160;        // 4*NC*132           = 33792
    float* TM       = ws + 3581952;        // 4*4096             = 16384
    int*   bar      = (int*)(ws + 3598336);// 3 ints (barrier counters)

    // zero the single-use barrier counters (graph-capturable async memset)
    hipMemsetAsync(bar, 0, 3 * sizeof(int), stream);

    fused_kernel<<<NBLK, NTHR, 0, stream>>>(x1, x2, x3, x4, wq, bq, wk, bk,
                                            Q, Kp, S, chunkSum, chunkOff, TM,
                                            bar, (float*)d_out);
}

// Round 9
// 121.257 us; speedup vs baseline: 1.6758x; 1.0095x over previous
//
#include <hip/hip_runtime.h>

#define T 4096
#define D 66
#define NL 3
#define NC 64          // scan chunks per modality
#define JC 64          // T / NC
#define HS 36          // ht row stride (32 rows + pad, multiple of 4 for b128)
#define WS 68          // W LDS col stride (multiple of 4 for b128)
#define DD (D * D)     // 4356
#define NBLK 320
#define NTHR 256
#define UNIT_F (2 * D * HS + D * WS)   // 9240 floats per MLP unit

// ---------------------------------------------------------------------------
// Coherent poll: global_load with sc0 sc1 bypasses L1 AND the XCD-local L2,
// reading the counter at the cross-XCD coherence point. No cache invalidate
// (R7's bug: buffer_inv per poll) and no stale XCD-L2 copy (R8's bug: ~35 us
// eviction-limited staleness per barrier).
// ---------------------------------------------------------------------------
__device__ __forceinline__ int coherent_poll(const int* p) {
    int v;
    asm volatile("global_load_dword %0, %1, off sc0 sc1\n\t"
                 "s_waitcnt vmcnt(0)"
                 : "=v"(v) : "v"(p) : "memory");
    return v;
}

// ---------------------------------------------------------------------------
// Device-scope grid barrier (single-use counter, zeroed by host memset before
// launch). Capacity proof: LDS 74,240 B/block -> 2 blocks/CU (160 KiB LDS),
// 256 CU * 2 = 512 >= 320 blocks: all blocks co-resident (R7/R8 occupancy
// counters confirmed), spin cannot deadlock. Release on the add writes back
// dirty L2 (phase handoff); one agent-acquire fence after exit invalidates
// this XCD's caches once.
// ---------------------------------------------------------------------------
__device__ __forceinline__ void grid_barrier(int* cnt) {
    __syncthreads();
    if (threadIdx.x == 0) {
        __hip_atomic_fetch_add(cnt, 1, __ATOMIC_RELEASE, __HIP_MEMORY_SCOPE_AGENT);
        while (coherent_poll(cnt) < NBLK)
            __builtin_amdgcn_s_sleep(8);
        __builtin_amdgcn_fence(__ATOMIC_ACQUIRE, "agent");
    }
    __syncthreads();
}

// ---------------------------------------------------------------------------
// One persistent kernel, 4 phases separated by grid_barrier():
//  P1 MLP: 640 2-wave units (5 jobs x 128 tiles of 32 rows), 2 units/block.
//  P2 scan: blocks 0..255 = (m, chunk); thread c<132 owns state column c.
//  P3 chunk-offset: 528 wave-units (m, c); lane=chunk, shuffle scan.
//  P4 out: 1280 waves x 3-4 rows; 2-round ballot search + 132-float dot.
// ---------------------------------------------------------------------------
__global__ __launch_bounds__(NTHR) void fused_kernel(
    const float* __restrict__ x1, const float* __restrict__ x2,
    const float* __restrict__ x3, const float* __restrict__ x4,
    const float* __restrict__ wq, const float* __restrict__ bq,
    const float* __restrict__ wk, const float* __restrict__ bk,
    float* __restrict__ Q, float* __restrict__ Kp,
    float* __restrict__ S, float* __restrict__ chunkSum,
    float* __restrict__ chunkOff, float* __restrict__ TM,
    int* __restrict__ bar, float* __restrict__ out)
{
    __shared__ float smem[2][UNIT_F];

    // ================= Phase 1: MLP =================
    {
        const int u    = threadIdx.x >> 7;       // unit slot 0/1
        const int t    = threadIdx.x & 127;
        const int unit = blockIdx.x * 2 + u;     // 0..639
        const int job  = unit >> 7;              // 0: Q; 1..4: K_{job-1}
        const int tile = unit & 127;             // 32-row tile
        const float* X = (job <= 1) ? x1 : (job == 2 ? x2 : (job == 3 ? x3 : x4));
        const float* W = (job == 0) ? wq : wk;
        const float* Bs = (job == 0) ? bq : bk;
        float* ht = smem[u];                     // [2][D*HS]
        float* Wl = smem[u] + 2 * D * HS;        // [D*WS]

        // stage x tile transposed: ht[0][d*HS + r]
        const float* xt = X + (size_t)tile * 32 * D;
#pragma unroll 4
        for (int k = t; k < 32 * D; k += 128) {
            const int r = k / D;
            const int d = k - r * D;
            ht[d * HS + r] = xt[k];
        }

        // prefetch layer-0 weights into registers
        float wreg[35];
#pragma unroll
        for (int i = 0; i < 35; ++i) {
            const int k = t + i * 128;
            if (k < DD) wreg[i] = W[k];
        }

        const int lane = t & 63;
        const int wv   = t >> 6;
        const int og   = lane & 15;
        const int rg   = lane >> 4;
        const int r0   = wv * 16 + rg * 4;
        const int c0   = og * 4;

        int src = 0;
#pragma unroll 1
        for (int l = 0; l < NL; ++l) {
#pragma unroll
            for (int i = 0; i < 35; ++i) {
                const int k = t + i * 128;
                if (k < DD) {
                    const int d = k / D;
                    const int o = k - d * D;
                    Wl[d * WS + o] = wreg[i];
                }
            }
            __syncthreads();

            if (l < NL - 1) {
                const float* Wg = W + (l + 1) * DD;
#pragma unroll
                for (int i = 0; i < 35; ++i) {
                    const int k = t + i * 128;
                    if (k < DD) wreg[i] = Wg[k];
                }
            }

            float acc[4][4];
            float acce[4];
            {
                const float b0 = Bs[l * D + c0 + 0];
                const float b1 = Bs[l * D + c0 + 1];
                const float b2 = Bs[l * D + c0 + 2];
                const float b3 = Bs[l * D + c0 + 3];
                const float be = Bs[l * D + 64 + (og & 1)];
#pragma unroll
                for (int ri = 0; ri < 4; ++ri) {
                    acc[ri][0] = b0; acc[ri][1] = b1;
                    acc[ri][2] = b2; acc[ri][3] = b3;
                    acce[ri] = be;
                }
            }

            const float* hs = ht + src * (D * HS);
#pragma unroll 6
            for (int d = 0; d < D; ++d) {
                const float4 h4 = *(const float4*)&hs[d * HS + r0];
                const float4 w4 = *(const float4*)&Wl[d * WS + c0];
                const float we  = Wl[d * WS + 64 + (og & 1)];
                const float hv[4] = {h4.x, h4.y, h4.z, h4.w};
#pragma unroll
                for (int ri = 0; ri < 4; ++ri) {
                    acc[ri][0] = fmaf(hv[ri], w4.x, acc[ri][0]);
                    acc[ri][1] = fmaf(hv[ri], w4.y, acc[ri][1]);
                    acc[ri][2] = fmaf(hv[ri], w4.z, acc[ri][2]);
                    acc[ri][3] = fmaf(hv[ri], w4.w, acc[ri][3]);
                    acce[ri]   = fmaf(hv[ri], we,  acce[ri]);
                }
            }

            if (l < NL - 1) {
                const int nb = 1 - src;
                float* hn = ht + nb * (D * HS);
#pragma unroll
                for (int ri = 0; ri < 4; ++ri) {
#pragma unroll
                    for (int ci = 0; ci < 4; ++ci)
                        hn[(c0 + ci) * HS + r0 + ri] = fmaxf(acc[ri][ci], 0.0f);
                    if (og < 2)
                        hn[(64 + og) * HS + r0 + ri] = fmaxf(acce[ri], 0.0f);
                }
                __syncthreads();
                src = nb;
            } else {
                float* outp = (job == 0) ? Q : (Kp + (size_t)(job - 1) * T * D);
#pragma unroll
                for (int ri = 0; ri < 4; ++ri) {
                    const int row = tile * 32 + r0 + ri;
                    float* rp = outp + (size_t)row * D + c0;
                    *(float2*)rp       = make_float2(acc[ri][0], acc[ri][1]);
                    *((float2*)rp + 1) = make_float2(acc[ri][2], acc[ri][3]);
                    if (og < 2) outp[(size_t)row * D + 64 + og] = acce[ri];
                }
            }
        }
    }

    grid_barrier(bar + 0);

    // ================= Phase 2: in-chunk scan + TM extract =================
    if (blockIdx.x < NC * 4) {
        const int ch = blockIdx.x & 63;
        const int m  = blockIdx.x >> 6;
        const int c  = threadIdx.x;
        const float* Xm = (m == 0) ? x1 : (m == 1 ? x2 : (m == 2 ? x3 : x4));
        const int j0 = ch * JC;

        if (c >= 144 && c < 144 + JC) {
            const int j = j0 + (c - 144);
            TM[m * T + j] = Xm[(size_t)j * D + (D - 1)];
        }
        if (c < 132) {
            const float* Km = Kp + (size_t)m * T * D;
            const int d = c >> 1;
            const int v = c & 1;
            float run = 0.0f;
#pragma unroll 8
            for (int jj = 0; jj < JC; ++jj) {
                const int j = j0 + jj;
                run = fmaf(Km[(size_t)j * D + d], Xm[(size_t)j * D + v], run);
                S[((size_t)m * T + j) * 132 + c] = run;
            }
            chunkSum[((size_t)m * NC + ch) * 132 + c] = run;
        }
    }

    grid_barrier(bar + 1);

    // ================= Phase 3: chunk-offset shuffle scan =================
    {
        const int wv   = threadIdx.x >> 6;
        const int lane = threadIdx.x & 63;           // chunk index (NC == 64)
        const int gw   = blockIdx.x * 4 + wv;        // 0..1279
        const int m    = gw & 3;
        const int c    = gw >> 2;
        if (c < 132) {
            const float v = chunkSum[((size_t)m * NC + lane) * 132 + c];
            float inc = v;
#pragma unroll
            for (int off = 1; off < 64; off <<= 1) {
                const float y = __shfl_up(inc, off);
                if (lane >= off) inc += y;
            }
            chunkOff[((size_t)m * NC + lane) * 132 + c] = inc - v;
        }
    }

    grid_barrier(bar + 2);

    // ================= Phase 4: gather + dot =================
    {
        float* segEnd = smem[0];                     // 4*64 floats, reuse LDS
        const int wv   = threadIdx.x >> 6;
        const int lane = threadIdx.x & 63;
        segEnd[wv * 64 + lane] = TM[wv * T + lane * 64 + 63];
        __syncthreads();

        for (int i = blockIdx.x * 4 + wv; i < T; i += NBLK * 4) {
            const float t1i = TM[i];                 // modality 0 times == t1
            const float q0  = Q[(size_t)i * D + lane];
            const float q1  = (lane < 2) ? Q[(size_t)i * D + 64 + lane] : 0.0f;
            float acc0 = 0.0f, acc1 = 0.0f;

            int seg[4];
#pragma unroll
            for (int m = 0; m < 4; ++m) {
                const unsigned long long b = __ballot(segEnd[m * 64 + lane] <= t1i);
                const int hi = __popcll(b);
                seg[m] = (hi < 63) ? hi : 63;
            }
            int idx[4];
#pragma unroll
            for (int m = 0; m < 4; ++m) {
                const float sv = TM[m * T + seg[m] * 64 + lane];
                const unsigned long long b = __ballot(sv <= t1i);
                idx[m] = seg[m] * 64 + __popcll(b) - 1;   // pos-1; -1 => none
            }

#pragma unroll
            for (int m = 0; m < 4; ++m) {
                if (idx[m] >= 0) {
                    const float* sp = S + ((size_t)m * T + idx[m]) * 132;
                    const float* op = chunkOff + ((size_t)m * NC + (idx[m] / JC)) * 132;
                    const float2 s0 = *(const float2*)(sp + lane * 2);
                    const float2 c0 = *(const float2*)(op + lane * 2);
                    acc0 = fmaf(q0, s0.x + c0.x, acc0);
                    acc1 = fmaf(q0, s0.y + c0.y, acc1);
                    if (lane < 2) {
                        const float2 s1 = *(const float2*)(sp + 128 + lane * 2);
                        const float2 c1 = *(const float2*)(op + 128 + lane * 2);
                        acc0 = fmaf(q1, s1.x + c1.x, acc0);
                        acc1 = fmaf(q1, s1.y + c1.y, acc1);
                    }
                }
            }

#pragma unroll
            for (int off = 32; off >= 1; off >>= 1) {
                acc0 += __shfl_down(acc0, off);
                acc1 += __shfl_down(acc1, off);
            }
            if (lane == 0) {
                out[(size_t)i * 2 + 0] = acc0;
                out[(size_t)i * 2 + 1] = acc1;
            }
        }
    }
}

extern "C" void kernel_launch(void* const* d_in, const int* in_sizes, int n_in,
                              void* d_out, int out_size, void* d_ws, size_t ws_size,
                              hipStream_t stream)
{
    (void)in_sizes; (void)n_in; (void)out_size; (void)ws_size;
    const float* x1 = (const float*)d_in[0];
    const float* x2 = (const float*)d_in[1];
    const float* x3 = (const float*)d_in[2];
    const float* x4 = (const float*)d_in[3];
    const float* wq = (const float*)d_in[4];
    const float* bq = (const float*)d_in[5];
    const float* wk = (const float*)d_in[6];
    const float* bk = (const float*)d_in[7];

    float* ws = (float*)d_ws;
    float* Q        = ws;                  // 4096*66            = 270336
    float* Kp       = ws + 270336;         // 4*4096*66          = 1081344
    float* S        = ws + 1351680;        // 4*4096*132         = 2162688
    float* chunkSum = ws + 3514368;        // 4*NC*132           = 33792
    float* chunkOff = ws + 3548160;        // 4*NC*132           = 33792
    float* TM       = ws + 3581952;        // 4*4096             = 16384
    int*   bar      = (int*)(ws + 3598336);// 3 ints (barrier counters)

    // zero the single-use barrier counters (graph-capturable async memset)
    hipMemsetAsync(bar, 0, 3 * sizeof(int), stream);

    fused_kernel<<<NBLK, NTHR, 0, stream>>>(x1, x2, x3, x4, wq, bq, wk, bk,
                                            Q, Kp, S, chunkSum, chunkOff, TM,
                                            bar, (float*)d_out);
}

// Round 10
// 97.597 us; speedup vs baseline: 2.0820x; 1.2424x over previous
//
#include <hip/hip_runtime.h>

#define T 4096
#define D 66
#define NL 3
#define NC 64          // scan chunks per modality
#define JC 64          // T / NC
#define HS 36          // ht row stride (32 rows + pad, multiple of 4 for b128)
#define WS 68          // W LDS col stride (multiple of 4 for b128)
#define DD (D * D)     // 4356
#define NBLK 320
#define NTHR 256
#define UNIT_F (2 * D * HS + D * WS)   // 9240 floats per MLP unit

typedef float f32x2 __attribute__((ext_vector_type(2)));

// ---------------------------------------------------------------------------
// Write-through stores for phase-handoff data: sc0 sc1 puts the data at the
// cross-XCD coherence point directly (bypasses the non-coherent XCD L2), so
// the grid barrier needs NO buffer_wbl2 (R8/R9's hidden ~35us/barrier cost:
// every block's release-add emitted a full L2 dirty-writeback) and NO
// buffer_inv on exit (consumers first-touch each handoff line after the
// barrier; across graph replays the dispatch AQL acquire invalidates L2 --
// the same mechanism that made the 4-kernel split correct with no fences).
// No "memory" clobber: these never alias anything read before the barrier,
// and the barrier's own volatile asm orders them via vmcnt.
// ---------------------------------------------------------------------------
__device__ __forceinline__ void st_sc(float* p, float v) {
    asm volatile("global_store_dword %0, %1, off sc0 sc1" :: "v"(p), "v"(v));
}
__device__ __forceinline__ void st2_sc(float* p, f32x2 v) {
    asm volatile("global_store_dwordx2 %0, %1, off sc0 sc1" :: "v"(p), "v"(v));
}

// sc0 sc1 load: reads the coherence point (no cache invalidate, no staleness)
__device__ __forceinline__ int coherent_poll(const int* p) {
    int v;
    asm volatile("global_load_dword %0, %1, off sc0 sc1\n\t"
                 "s_waitcnt vmcnt(0)"
                 : "=v"(v) : "v"(p) : "memory");
    return v;
}

// ---------------------------------------------------------------------------
// Fence-free grid barrier. Every wave drains its own vmcnt (covers the inline
// asm sc-stores the compiler cannot see), then lane 0 does a RELAXED add (no
// cache maintenance instructions) and polls at the coherence point.
// Capacity proof: LDS 74,240 B/block -> 2 blocks/CU, 512 >= 320 blocks
// co-resident (R7-R9 occupancy confirmed); spin cannot deadlock.
// ---------------------------------------------------------------------------
__device__ __forceinline__ void grid_barrier(int* cnt) {
    asm volatile("s_waitcnt vmcnt(0)" ::: "memory");   // per-wave store drain
    __syncthreads();
    if (threadIdx.x == 0) {
        __hip_atomic_fetch_add(cnt, 1, __ATOMIC_RELAXED, __HIP_MEMORY_SCOPE_AGENT);
        while (coherent_poll(cnt) < NBLK)
            __builtin_amdgcn_s_sleep(4);
    }
    __syncthreads();
}

// ---------------------------------------------------------------------------
// One persistent kernel, 4 phases separated by grid_barrier():
//  P1 MLP: 640 2-wave units (5 jobs x 128 tiles of 32 rows), 2 units/block.
//  P2 scan: blocks 0..255 = (m, chunk); thread c<132 owns state column c.
//  P3 chunk-offset: 528 wave-units (m, c); lane=chunk, shuffle scan.
//  P4 out: 1280 waves x 3-4 rows; 2-round ballot search + 132-float dot.
// ---------------------------------------------------------------------------
__global__ __launch_bounds__(NTHR) void fused_kernel(
    const float* __restrict__ x1, const float* __restrict__ x2,
    const float* __restrict__ x3, const float* __restrict__ x4,
    const float* __restrict__ wq, const float* __restrict__ bq,
    const float* __restrict__ wk, const float* __restrict__ bk,
    float* __restrict__ Q, float* __restrict__ Kp,
    float* __restrict__ S, float* __restrict__ chunkSum,
    float* __restrict__ chunkOff, float* __restrict__ TM,
    int* __restrict__ bar, float* __restrict__ out)
{
    __shared__ float smem[2][UNIT_F];

    // ================= Phase 1: MLP =================
    {
        const int u    = threadIdx.x >> 7;       // unit slot 0/1
        const int t    = threadIdx.x & 127;
        const int unit = blockIdx.x * 2 + u;     // 0..639
        const int job  = unit >> 7;              // 0: Q; 1..4: K_{job-1}
        const int tile = unit & 127;             // 32-row tile
        const float* X = (job <= 1) ? x1 : (job == 2 ? x2 : (job == 3 ? x3 : x4));
        const float* W = (job == 0) ? wq : wk;
        const float* Bs = (job == 0) ? bq : bk;
        float* ht = smem[u];                     // [2][D*HS]
        float* Wl = smem[u] + 2 * D * HS;        // [D*WS]

        // stage x tile transposed: ht[0][d*HS + r]
        const float* xt = X + (size_t)tile * 32 * D;
#pragma unroll 4
        for (int k = t; k < 32 * D; k += 128) {
            const int r = k / D;
            const int d = k - r * D;
            ht[d * HS + r] = xt[k];
        }

        // prefetch layer-0 weights into registers
        float wreg[35];
#pragma unroll
        for (int i = 0; i < 35; ++i) {
            const int k = t + i * 128;
            if (k < DD) wreg[i] = W[k];
        }

        const int lane = t & 63;
        const int wv   = t >> 6;
        const int og   = lane & 15;
        const int rg   = lane >> 4;
        const int r0   = wv * 16 + rg * 4;
        const int c0   = og * 4;

        int src = 0;
#pragma unroll 1
        for (int l = 0; l < NL; ++l) {
#pragma unroll
            for (int i = 0; i < 35; ++i) {
                const int k = t + i * 128;
                if (k < DD) {
                    const int d = k / D;
                    const int o = k - d * D;
                    Wl[d * WS + o] = wreg[i];
                }
            }
            __syncthreads();

            if (l < NL - 1) {
                const float* Wg = W + (l + 1) * DD;
#pragma unroll
                for (int i = 0; i < 35; ++i) {
                    const int k = t + i * 128;
                    if (k < DD) wreg[i] = Wg[k];
                }
            }

            float acc[4][4];
            float acce[4];
            {
                const float b0 = Bs[l * D + c0 + 0];
                const float b1 = Bs[l * D + c0 + 1];
                const float b2 = Bs[l * D + c0 + 2];
                const float b3 = Bs[l * D + c0 + 3];
                const float be = Bs[l * D + 64 + (og & 1)];
#pragma unroll
                for (int ri = 0; ri < 4; ++ri) {
                    acc[ri][0] = b0; acc[ri][1] = b1;
                    acc[ri][2] = b2; acc[ri][3] = b3;
                    acce[ri] = be;
                }
            }

            const float* hs = ht + src * (D * HS);
#pragma unroll 6
            for (int d = 0; d < D; ++d) {
                const float4 h4 = *(const float4*)&hs[d * HS + r0];
                const float4 w4 = *(const float4*)&Wl[d * WS + c0];
                const float we  = Wl[d * WS + 64 + (og & 1)];
                const float hv[4] = {h4.x, h4.y, h4.z, h4.w};
#pragma unroll
                for (int ri = 0; ri < 4; ++ri) {
                    acc[ri][0] = fmaf(hv[ri], w4.x, acc[ri][0]);
                    acc[ri][1] = fmaf(hv[ri], w4.y, acc[ri][1]);
                    acc[ri][2] = fmaf(hv[ri], w4.z, acc[ri][2]);
                    acc[ri][3] = fmaf(hv[ri], w4.w, acc[ri][3]);
                    acce[ri]   = fmaf(hv[ri], we,  acce[ri]);
                }
            }

            if (l < NL - 1) {
                const int nb = 1 - src;
                float* hn = ht + nb * (D * HS);
#pragma unroll
                for (int ri = 0; ri < 4; ++ri) {
#pragma unroll
                    for (int ci = 0; ci < 4; ++ci)
                        hn[(c0 + ci) * HS + r0 + ri] = fmaxf(acc[ri][ci], 0.0f);
                    if (og < 2)
                        hn[(64 + og) * HS + r0 + ri] = fmaxf(acce[ri], 0.0f);
                }
                __syncthreads();
                src = nb;
            } else {
                // handoff stores: write-through to the coherence point
                float* outp = (job == 0) ? Q : (Kp + (size_t)(job - 1) * T * D);
#pragma unroll
                for (int ri = 0; ri < 4; ++ri) {
                    const int row = tile * 32 + r0 + ri;
                    float* rp = outp + (size_t)row * D + c0;
                    f32x2 v01 = {acc[ri][0], acc[ri][1]};
                    f32x2 v23 = {acc[ri][2], acc[ri][3]};
                    st2_sc(rp, v01);
                    st2_sc(rp + 2, v23);
                    if (og < 2) st_sc(outp + (size_t)row * D + 64 + og, acce[ri]);
                }
            }
        }
    }

    grid_barrier(bar + 0);

    // ================= Phase 2: in-chunk scan + TM extract =================
    if (blockIdx.x < NC * 4) {
        const int ch = blockIdx.x & 63;
        const int m  = blockIdx.x >> 6;
        const int c  = threadIdx.x;
        const float* Xm = (m == 0) ? x1 : (m == 1 ? x2 : (m == 2 ? x3 : x4));
        const int j0 = ch * JC;

        if (c >= 144 && c < 144 + JC) {
            const int j = j0 + (c - 144);
            st_sc(TM + m * T + j, Xm[(size_t)j * D + (D - 1)]);
        }
        if (c < 132) {
            const float* Km = Kp + (size_t)m * T * D;
            const int d = c >> 1;
            const int v = c & 1;
            float run = 0.0f;
#pragma unroll 8
            for (int jj = 0; jj < JC; ++jj) {
                const int j = j0 + jj;
                run = fmaf(Km[(size_t)j * D + d], Xm[(size_t)j * D + v], run);
                st_sc(S + ((size_t)m * T + j) * 132 + c, run);
            }
            st_sc(chunkSum + ((size_t)m * NC + ch) * 132 + c, run);
        }
    }

    grid_barrier(bar + 1);

    // ================= Phase 3: chunk-offset shuffle scan =================
    {
        const int wv   = threadIdx.x >> 6;
        const int lane = threadIdx.x & 63;           // chunk index (NC == 64)
        const int gw   = blockIdx.x * 4 + wv;        // 0..1279
        const int m    = gw & 3;
        const int c    = gw >> 2;
        if (c < 132) {
            const float v = chunkSum[((size_t)m * NC + lane) * 132 + c];
            float inc = v;
#pragma unroll
            for (int off = 1; off < 64; off <<= 1) {
                const float y = __shfl_up(inc, off);
                if (lane >= off) inc += y;
            }
            st_sc(chunkOff + ((size_t)m * NC + lane) * 132 + c, inc - v);
        }
    }

    grid_barrier(bar + 2);

    // ================= Phase 4: gather + dot =================
    {
        float* segEnd = smem[0];                     // 4*64 floats, reuse LDS
        const int wv   = threadIdx.x >> 6;
        const int lane = threadIdx.x & 63;
        segEnd[wv * 64 + lane] = TM[wv * T + lane * 64 + 63];
        __syncthreads();

        for (int i = blockIdx.x * 4 + wv; i < T; i += NBLK * 4) {
            const float t1i = TM[i];                 // modality 0 times == t1
            const float q0  = Q[(size_t)i * D + lane];
            const float q1  = (lane < 2) ? Q[(size_t)i * D + 64 + lane] : 0.0f;
            float acc0 = 0.0f, acc1 = 0.0f;

            int seg[4];
#pragma unroll
            for (int m = 0; m < 4; ++m) {
                const unsigned long long b = __ballot(segEnd[m * 64 + lane] <= t1i);
                const int hi = __popcll(b);
                seg[m] = (hi < 63) ? hi : 63;
            }
            int idx[4];
#pragma unroll
            for (int m = 0; m < 4; ++m) {
                const float sv = TM[m * T + seg[m] * 64 + lane];
                const unsigned long long b = __ballot(sv <= t1i);
                idx[m] = seg[m] * 64 + __popcll(b) - 1;   // pos-1; -1 => none
            }

#pragma unroll
            for (int m = 0; m < 4; ++m) {
                if (idx[m] >= 0) {
                    const float* sp = S + ((size_t)m * T + idx[m]) * 132;
                    const float* op = chunkOff + ((size_t)m * NC + (idx[m] / JC)) * 132;
                    const float2 s0 = *(const float2*)(sp + lane * 2);
                    const float2 c0 = *(const float2*)(op + lane * 2);
                    acc0 = fmaf(q0, s0.x + c0.x, acc0);
                    acc1 = fmaf(q0, s0.y + c0.y, acc1);
                    if (lane < 2) {
                        const float2 s1 = *(const float2*)(sp + 128 + lane * 2);
                        const float2 c1 = *(const float2*)(op + 128 + lane * 2);
                        acc0 = fmaf(q1, s1.x + c1.x, acc0);
                        acc1 = fmaf(q1, s1.y + c1.y, acc1);
                    }
                }
            }

#pragma unroll
            for (int off = 32; off >= 1; off >>= 1) {
                acc0 += __shfl_down(acc0, off);
                acc1 += __shfl_down(acc1, off);
            }
            if (lane == 0) {
                out[(size_t)i * 2 + 0] = acc0;
                out[(size_t)i * 2 + 1] = acc1;
            }
        }
    }
}

extern "C" void kernel_launch(void* const* d_in, const int* in_sizes, int n_in,
                              void* d_out, int out_size, void* d_ws, size_t ws_size,
                              hipStream_t stream)
{
    (void)in_sizes; (void)n_in; (void)out_size; (void)ws_size;
    const float* x1 = (const float*)d_in[0];
    const float* x2 = (const float*)d_in[1];
    const float* x3 = (const float*)d_in[2];
    const float* x4 = (const float*)d_in[3];
    const float* wq = (const float*)d_in[4];
    const float* bq = (const float*)d_in[5];
    const float* wk = (const float*)d_in[6];
    const float* bk = (const float*)d_in[7];

    float* ws = (float*)d_ws;
    float* Q        = ws;                  // 4096*66            = 270336
    float* Kp       = ws + 270336;         // 4*4096*66          = 1081344
    float* S        = ws + 1351680;        // 4*4096*132         = 2162688
    float* chunkSum = ws + 3514368;        // 4*NC*132           = 33792
    float* chunkOff = ws + 3548160;        // 4*NC*132           = 33792
    float* TM       = ws + 3581952;        // 4*4096             = 16384
    int*   bar      = (int*)(ws + 3598336);// 3 ints (barrier counters)

    // zero the single-use barrier counters (graph-capturable async memset)
    hipMemsetAsync(bar, 0, 3 * sizeof(int), stream);

    fused_kernel<<<NBLK, NTHR, 0, stream>>>(x1, x2, x3, x4, wq, bq, wk, bk,
                                            Q, Kp, S, chunkSum, chunkOff, TM,
                                            bar, (float*)d_out);
}

// Round 11
// 33.752 us; speedup vs baseline: 6.0203x; 2.8916x over previous
//
#include <hip/hip_runtime.h>

#define T 4096
#define D 66
#define NL 3
#define NC 64          // scan chunks per modality (= K1 blocks per modality)
#define JC 64          // rows per chunk
#define HS 68          // ht row stride: 64 rows + 4 pad (multiple of 4 for b128)
#define WS 68          // W LDS col stride (multiple of 4 for b128)
#define DD (D * D)     // 4356

// ---------------------------------------------------------------------------
// Kernel 1: fused MLP + in-chunk scan. 320 blocks x 256 threads (4 waves).
//   Blocks 0..255  = (m = blk>>6, ch = blk&63): 64-row MLP of modality m
//     with K kept ENTIRELY in LDS (transposed [d][row]), then the scan phase
//     reads K columns from LDS and writes S (relative cumsum), chunkSum, TM.
//     K_m never touches global memory -- this was the only cross-kernel
//     dependency that forced a separate scan launch in the R5 split.
//   Blocks 256..319 = Q tiles (64 rows each): same MLP, writes Q to global.
// MLP: register-tiled 4x4 outer product, lane (rg,og) owns rows r0..r0+3
// (r0 = wv*16+rg*4, 4 waves cover 64 rows) and cols og*4..og*4+3 (+cols
// 64/65 for og<2). Weights prefetched one layer ahead into 18 regs/thread;
// one Wl stage shared by all 4 waves (half the staging of 2-wave blocks).
// LDS: ht 2*66*68 + Wl 66*68 floats = 53,856 B -> 2 blocks/CU, 320 blocks
// all co-resident.
// ---------------------------------------------------------------------------
__global__ __launch_bounds__(256) void mlp_scan_kernel(
    const float* __restrict__ x1, const float* __restrict__ x2,
    const float* __restrict__ x3, const float* __restrict__ x4,
    const float* __restrict__ wq, const float* __restrict__ bq,
    const float* __restrict__ wk, const float* __restrict__ bk,
    float* __restrict__ Q, float* __restrict__ S,
    float* __restrict__ chunkSum, float* __restrict__ TM)
{
    __shared__ float ht[2][D * HS];
    __shared__ float Wl[D * WS];
    const int t    = threadIdx.x;
    const bool isQ = blockIdx.x >= 256;
    const int m    = isQ ? 0 : (blockIdx.x >> 6);          // modality
    const int j0   = (isQ ? (blockIdx.x - 256) : (blockIdx.x & 63)) * 64;
    const float* X = (isQ || m == 0) ? x1 : (m == 1 ? x2 : (m == 2 ? x3 : x4));
    const float* W = isQ ? wq : wk;
    const float* Bs = isQ ? bq : bk;

    // stage 64-row x tile transposed: ht[0][d*HS + r]
    const float* xt = X + (size_t)j0 * D;
#pragma unroll 4
    for (int k = t; k < 64 * D; k += 256) {
        const int r = k / D;
        const int d = k - r * D;
        ht[0][d * HS + r] = xt[k];
    }

    // prefetch layer-0 weights into registers (in flight with x staging)
    float wreg[18];
#pragma unroll
    for (int i = 0; i < 18; ++i) {
        const int k = t + i * 256;
        if (k < DD) wreg[i] = W[k];
    }

    const int lane = t & 63;
    const int wv   = t >> 6;
    const int og   = lane & 15;
    const int rg   = lane >> 4;
    const int r0   = wv * 16 + rg * 4;     // rows r0..r0+3 (wv covers 64)
    const int c0   = og * 4;               // cols c0..c0+3

    int src = 0;
#pragma unroll 1
    for (int l = 0; l < NL; ++l) {
        // write prefetched weights into LDS (stride WS), shared by 4 waves
#pragma unroll
        for (int i = 0; i < 18; ++i) {
            const int k = t + i * 256;
            if (k < DD) {
                const int d = k / D;
                const int o = k - d * D;
                Wl[d * WS + o] = wreg[i];
            }
        }
        __syncthreads();

        // prefetch next layer's weights (latency hides under this d-loop)
        if (l < NL - 1) {
            const float* Wg = W + (l + 1) * DD;
#pragma unroll
            for (int i = 0; i < 18; ++i) {
                const int k = t + i * 256;
                if (k < DD) wreg[i] = Wg[k];
            }
        }

        float acc[4][4];
        float acce[4];
        {
            const float b0 = Bs[l * D + c0 + 0];
            const float b1 = Bs[l * D + c0 + 1];
            const float b2 = Bs[l * D + c0 + 2];
            const float b3 = Bs[l * D + c0 + 3];
            const float be = Bs[l * D + 64 + (og & 1)];
#pragma unroll
            for (int ri = 0; ri < 4; ++ri) {
                acc[ri][0] = b0; acc[ri][1] = b1;
                acc[ri][2] = b2; acc[ri][3] = b3;
                acce[ri] = be;
            }
        }

        const float* hs = ht[src];
#pragma unroll 6
        for (int d = 0; d < D; ++d) {
            const float4 h4 = *(const float4*)&hs[d * HS + r0];
            const float4 w4 = *(const float4*)&Wl[d * WS + c0];
            const float we  = Wl[d * WS + 64 + (og & 1)];
            const float hv[4] = {h4.x, h4.y, h4.z, h4.w};
#pragma unroll
            for (int ri = 0; ri < 4; ++ri) {
                acc[ri][0] = fmaf(hv[ri], w4.x, acc[ri][0]);
                acc[ri][1] = fmaf(hv[ri], w4.y, acc[ri][1]);
                acc[ri][2] = fmaf(hv[ri], w4.z, acc[ri][2]);
                acc[ri][3] = fmaf(hv[ri], w4.w, acc[ri][3]);
                acce[ri]   = fmaf(hv[ri], we,  acce[ri]);
            }
        }

        if (l < NL - 1 || !isQ) {
            // intermediate layers (relu) and the K final layer (no relu)
            // land in the other LDS buffer
            const bool rel = (l < NL - 1);
            const int nb = 1 - src;
            float* hn = ht[nb];
#pragma unroll
            for (int ri = 0; ri < 4; ++ri) {
#pragma unroll
                for (int ci = 0; ci < 4; ++ci) {
                    const float v = acc[ri][ci];
                    hn[(c0 + ci) * HS + r0 + ri] = rel ? fmaxf(v, 0.0f) : v;
                }
                if (og < 2) {
                    const float v = acce[ri];
                    hn[(64 + og) * HS + r0 + ri] = rel ? fmaxf(v, 0.0f) : v;
                }
            }
            __syncthreads();
            src = nb;
        } else {
            // Q final layer -> global (row-major)
#pragma unroll
            for (int ri = 0; ri < 4; ++ri) {
                const int row = j0 + r0 + ri;
                float* rp = Q + (size_t)row * D + c0;
                *(float2*)rp       = make_float2(acc[ri][0], acc[ri][1]);
                *((float2*)rp + 1) = make_float2(acc[ri][2], acc[ri][3]);
                if (og < 2) Q[(size_t)row * D + 64 + og] = acce[ri];
            }
        }
    }

    // ===== scan phase (K blocks only): K is in ht[src] as [d][row] =====
    if (!isQ) {
        const int c = t;
        if (c >= 144 && c < 144 + JC) {
            const int j = j0 + (c - 144);
            TM[m * T + j] = X[(size_t)j * D + (D - 1)];
        }
        if (c < 132) {
            const int d = c >> 1;
            const int v = c & 1;
            const float* kcol = &ht[src][d * HS];
            float run = 0.0f;
#pragma unroll 8
            for (int jj = 0; jj < JC; ++jj) {
                run = fmaf(kcol[jj], X[(size_t)(j0 + jj) * D + v], run);
                S[((size_t)m * T + j0 + jj) * 132 + c] = run;
            }
            chunkSum[((size_t)m * NC + (j0 >> 6)) * 132 + c] = run;
        }
    }
}

// ---------------------------------------------------------------------------
// Kernel 2: exclusive scan of chunk sums, wave-parallel. One wave per
// (m, column c): lane ch gathers chunkSum[m][ch][c], 6-step shuffle scan,
// store exclusive prefix. Grid (33, 4).
// ---------------------------------------------------------------------------
__global__ __launch_bounds__(256) void chunkscan_kernel(
    const float* __restrict__ chunkSum, float* __restrict__ chunkOff)
{
    const int wv   = threadIdx.x >> 6;
    const int lane = threadIdx.x & 63;     // = chunk index ch (NC == 64)
    const int c    = blockIdx.x * 4 + wv;  // 0..131
    const int m    = blockIdx.y;
    if (c >= 132) return;

    const float v = chunkSum[((size_t)m * NC + lane) * 132 + c];
    float inc = v;
#pragma unroll
    for (int off = 1; off < 64; off <<= 1) {
        const float y = __shfl_up(inc, off);
        if (lane >= off) inc += y;
    }
    chunkOff[((size_t)m * NC + lane) * 132 + c] = inc - v;
}

// ---------------------------------------------------------------------------
// Kernel 3: one wave per output row i (4 rows/block). Block stages the 4x64
// segment-end table into LDS once; 2-round ballot search (2 dependent loads
// per modality), then lane-parallel dot of Q[i] with (S row + chunk offset
// row), shuffle-reduce, lane 0 writes the 2 outputs.
// ---------------------------------------------------------------------------
__global__ __launch_bounds__(256) void out_kernel(
    const float* __restrict__ Q, const float* __restrict__ S,
    const float* __restrict__ chunkOff, const float* __restrict__ TM,
    float* __restrict__ out)
{
    __shared__ float segEnd[4][64];
    const int w    = threadIdx.x >> 6;
    const int lane = threadIdx.x & 63;
    const int i    = blockIdx.x * 4 + w;

    segEnd[w][lane] = TM[w * T + lane * 64 + 63];   // wave w stages modality w
    const float t1i = TM[i];               // modality 0 times == t1
    const float q0  = Q[(size_t)i * D + lane];
    const float q1  = (lane < 2) ? Q[(size_t)i * D + 64 + lane] : 0.0f;
    float acc0 = 0.0f, acc1 = 0.0f;
    __syncthreads();

    int seg[4];
#pragma unroll
    for (int m = 0; m < 4; ++m) {
        const unsigned long long b = __ballot(segEnd[m][lane] <= t1i);
        const int hi = __popcll(b);
        seg[m] = (hi < 63) ? hi : 63;
    }
    int idx[4];
#pragma unroll
    for (int m = 0; m < 4; ++m) {
        const float sv = TM[m * T + seg[m] * 64 + lane];
        const unsigned long long b = __ballot(sv <= t1i);
        idx[m] = seg[m] * 64 + __popcll(b) - 1;   // pos-1; -1 => none
    }

#pragma unroll
    for (int m = 0; m < 4; ++m) {
        if (idx[m] >= 0) {
            const float* sp = S + ((size_t)m * T + idx[m]) * 132;
            const float* op = chunkOff + ((size_t)m * NC + (idx[m] / JC)) * 132;
            const float2 s0 = *(const float2*)(sp + lane * 2);
            const float2 c0 = *(const float2*)(op + lane * 2);
            acc0 = fmaf(q0, s0.x + c0.x, acc0);
            acc1 = fmaf(q0, s0.y + c0.y, acc1);
            if (lane < 2) {
                const float2 s1 = *(const float2*)(sp + 128 + lane * 2);
                const float2 c1 = *(const float2*)(op + 128 + lane * 2);
                acc0 = fmaf(q1, s1.x + c1.x, acc0);
                acc1 = fmaf(q1, s1.y + c1.y, acc1);
            }
        }
    }

#pragma unroll
    for (int off = 32; off >= 1; off >>= 1) {
        acc0 += __shfl_down(acc0, off);
        acc1 += __shfl_down(acc1, off);
    }
    if (lane == 0) {
        out[(size_t)i * 2 + 0] = acc0;
        out[(size_t)i * 2 + 1] = acc1;
    }
}

extern "C" void kernel_launch(void* const* d_in, const int* in_sizes, int n_in,
                              void* d_out, int out_size, void* d_ws, size_t ws_size,
                              hipStream_t stream)
{
    (void)in_sizes; (void)n_in; (void)out_size; (void)ws_size;
    const float* x1 = (const float*)d_in[0];
    const float* x2 = (const float*)d_in[1];
    const float* x3 = (const float*)d_in[2];
    const float* x4 = (const float*)d_in[3];
    const float* wq = (const float*)d_in[4];
    const float* bq = (const float*)d_in[5];
    const float* wk = (const float*)d_in[6];
    const float* bk = (const float*)d_in[7];

    float* ws = (float*)d_ws;
    float* Q        = ws;                  // 4096*66            = 270336
    float* S        = ws + 270336;         // 4*4096*132         = 2162688
    float* chunkSum = ws + 2433024;        // 4*NC*132           = 33792
    float* chunkOff = ws + 2466816;        // 4*NC*132           = 33792
    float* TM       = ws + 2500608;        // 4*4096             = 16384
                                           // total 2516992 floats ~ 10.07 MB

    mlp_scan_kernel<<<320, 256, 0, stream>>>(x1, x2, x3, x4, wq, bq, wk, bk,
                                             Q, S, chunkSum, TM);
    chunkscan_kernel<<<dim3(33, 4), 256, 0, stream>>>(chunkSum, chunkOff);
    out_kernel<<<1024, 256, 0, stream>>>(Q, S, chunkOff, TM, (float*)d_out);
}

// Round 12
// 29.514 us; speedup vs baseline: 6.8849x; 1.1436x over previous
//
#include <hip/hip_runtime.h>

#define T 4096
#define D 66
#define NL 3
#define NC 64          // scan chunks per modality
#define JC 64          // rows per chunk
#define DD (D * D)     // 4356
#define HSB 104        // H/Wt LDS stride in bf16 elems (16B multiple, 2-way-max banks)
#define KTS 68         // KT LDS stride (fp32)

typedef short bf16x8 __attribute__((ext_vector_type(8)));
typedef float f32x4  __attribute__((ext_vector_type(4)));

__device__ __forceinline__ short f2bf(float f) {   // RNE f32 -> bf16
    unsigned int u = __builtin_bit_cast(unsigned int, f);
    u += 0x7fff + ((u >> 16) & 1);
    return (short)(u >> 16);
}

// ---------------------------------------------------------------------------
// Kernel 1: fused MFMA-MLP + in-chunk scan. 320 blocks x 256 threads (4 waves).
//   Blocks 0..255 = (m, ch): 64-row MLP of modality m (K stays in LDS), then
//   scan of those 64 rows -> S/chunkSum/TM. Blocks 256..319 = Q tiles.
// MLP per layer: H [64][HSB] bf16 row-major (K-padded to 96 with zeros),
// W^T [80][HSB] bf16 (N-padded rows 66..79 zero). Wave wv owns row-tile mt=wv;
// 3 A-frags + 5x3 B-frags (ds_read_b128) -> 15 mfma_f32_16x16x32_bf16.
// Frag mapping: row/col = lane&15, k-group = (lane>>4)*8 (any bijective k-map
// is self-consistent since A and B use the same formula). D/C layout (m89):
// col = lane&15, row = (lane>>4)*4 + reg.
// Epilogue: +bias, relu, f2bf -> H (inner layers); layer 2 -> Q (global fp32)
// or KT[col][row] (LDS fp32) for the scan tail. V/ts columns held in a small
// LDS side buffer from the initial x staging (no scattered global re-reads).
// LDS: 13312 + 16640 + 17952 + 768 = 48,672 B.
// ---------------------------------------------------------------------------
__global__ __launch_bounds__(256) void mlp_scan_kernel(
    const float* __restrict__ x1, const float* __restrict__ x2,
    const float* __restrict__ x3, const float* __restrict__ x4,
    const float* __restrict__ wq, const float* __restrict__ bq,
    const float* __restrict__ wk, const float* __restrict__ bk,
    float* __restrict__ Q, float* __restrict__ S,
    float* __restrict__ chunkSum, float* __restrict__ TM)
{
    __shared__ short Hs[64 * HSB];
    __shared__ short Wt[80 * HSB];
    __shared__ float KT[D * KTS];
    __shared__ float side[3][64];          // [0],[1] = V cols; [2] = ts

    const int t    = threadIdx.x;
    const bool isQ = blockIdx.x >= 256;
    const int m    = isQ ? 0 : (blockIdx.x >> 6);
    const int j0   = (isQ ? (blockIdx.x - 256) : (blockIdx.x & 63)) * 64;
    const float* X  = (isQ || m == 0) ? x1 : (m == 1 ? x2 : (m == 2 ? x3 : x4));
    const float* W  = isQ ? wq : wk;
    const float* Bs = isQ ? bq : bk;

    // ---- stage x tile -> Hs (bf16) + side V/ts ----
    const float* xt = X + (size_t)j0 * D;
    for (int k = t; k < 64 * D; k += 256) {
        const int r = k / D;
        const int d = k - r * D;
        const float v = xt[k];
        Hs[r * HSB + d] = f2bf(v);
        if (d < 2) side[d][r] = v;
        if (d == D - 1) side[2][r] = v;
    }
    // zero Hs K-pad cols 66..103
    for (int k = t; k < 64 * (HSB - D); k += 256) {
        const int r = k / (HSB - D);
        const int d = D + (k - r * (HSB - D));
        Hs[r * HSB + d] = 0;
    }
    // zero Wt fully (pads persist; stages only overwrite [col<66][k<66])
    {
        int* wz = (int*)Wt;
        for (int k = t; k < 80 * HSB / 2; k += 256) wz[k] = 0;
    }

    // prefetch layer-0 weights (in flight with staging)
    float wreg[18];
#pragma unroll
    for (int i = 0; i < 18; ++i) {
        const int k = t + i * 256;
        if (k < DD) wreg[i] = W[k];
    }

    const int lane = t & 63;
    const int wv   = t >> 6;
    const int lrow = lane & 15;            // A row / B col within tile
    const int kg   = (lane >> 4) * 8;      // k-group base
    const int cr0  = (lane >> 4) * 4;      // D row base within tile

    __syncthreads();

#pragma unroll 1
    for (int l = 0; l < NL; ++l) {
        // stage W^T (bf16) for this layer
#pragma unroll
        for (int i = 0; i < 18; ++i) {
            const int k = t + i * 256;
            if (k < DD) {
                const int kk = k / D;          // input dim (K)
                const int o  = k - kk * D;     // output col (N)
                Wt[o * HSB + kk] = f2bf(wreg[i]);
            }
        }
        __syncthreads();

        // prefetch next layer's weights (hides under mfma phase)
        if (l < NL - 1) {
            const float* Wg = W + (l + 1) * DD;
#pragma unroll
            for (int i = 0; i < 18; ++i) {
                const int k = t + i * 256;
                if (k < DD) wreg[i] = Wg[k];
            }
        }

        // A fragments (row tile mt = wv), k-steps 0/32/64
        const int abase = (wv * 16 + lrow) * HSB + kg;
        const bf16x8 a0 = *(const bf16x8*)&Hs[abase];
        const bf16x8 a1 = *(const bf16x8*)&Hs[abase + 32];
        const bf16x8 a2 = *(const bf16x8*)&Hs[abase + 64];

        f32x4 acc[5];
#pragma unroll
        for (int nt = 0; nt < 5; ++nt) {
            const short* wb = &Wt[(nt * 16 + lrow) * HSB + kg];
            f32x4 c = {0.0f, 0.0f, 0.0f, 0.0f};
            c = __builtin_amdgcn_mfma_f32_16x16x32_bf16(a0, *(const bf16x8*)(wb),      c, 0, 0, 0);
            c = __builtin_amdgcn_mfma_f32_16x16x32_bf16(a1, *(const bf16x8*)(wb + 32), c, 0, 0, 0);
            c = __builtin_amdgcn_mfma_f32_16x16x32_bf16(a2, *(const bf16x8*)(wb + 64), c, 0, 0, 0);
            acc[nt] = c;
        }
        __syncthreads();   // all Hs/Wt reads of this layer complete

        // epilogue: bias (+relu+cvt -> Hs) or final store
#pragma unroll
        for (int nt = 0; nt < 5; ++nt) {
            const int col = nt * 16 + lrow;
            const float bias = (col < D) ? Bs[l * D + col] : 0.0f;
#pragma unroll
            for (int r = 0; r < 4; ++r) {
                const int row = wv * 16 + cr0 + r;
                float v = acc[nt][r] + bias;
                if (l < NL - 1) {
                    v = fmaxf(v, 0.0f);
                    Hs[row * HSB + col] = f2bf(v);   // pad cols write 0
                } else if (isQ) {
                    if (col < D) Q[(size_t)(j0 + row) * D + col] = v;
                } else {
                    if (col < D) KT[col * KTS + row] = v;
                }
            }
        }
    }

    __syncthreads();

    // ===== scan tail (K blocks): KT in LDS, V/ts from side buffer =====
    if (!isQ) {
        const int c = t;
        if (c >= 144 && c < 144 + JC) TM[m * T + j0 + (c - 144)] = side[2][c - 144];
        if (c < 132) {
            const int d = c >> 1;
            const int v = c & 1;
            float run = 0.0f;
#pragma unroll 8
            for (int jj = 0; jj < JC; ++jj) {
                run = fmaf(KT[d * KTS + jj], side[v][jj], run);
                S[((size_t)m * T + j0 + jj) * 132 + c] = run;
            }
            chunkSum[((size_t)m * NC + j0 / JC) * 132 + c] = run;
        }
    }
}

// ---------------------------------------------------------------------------
// Kernel 2: exclusive scan of chunk sums, wave-parallel (unchanged R11).
// ---------------------------------------------------------------------------
__global__ __launch_bounds__(256) void chunkscan_kernel(
    const float* __restrict__ chunkSum, float* __restrict__ chunkOff)
{
    const int wv   = threadIdx.x >> 6;
    const int lane = threadIdx.x & 63;     // chunk index (NC == 64)
    const int c    = blockIdx.x * 4 + wv;  // 0..131
    const int m    = blockIdx.y;
    if (c >= 132) return;

    const float v = chunkSum[((size_t)m * NC + lane) * 132 + c];
    float inc = v;
#pragma unroll
    for (int off = 1; off < 64; off <<= 1) {
        const float y = __shfl_up(inc, off);
        if (lane >= off) inc += y;
    }
    chunkOff[((size_t)m * NC + lane) * 132 + c] = inc - v;
}

// ---------------------------------------------------------------------------
// Kernel 3: gather + dot, one wave per output row (unchanged R11).
// ---------------------------------------------------------------------------
__global__ __launch_bounds__(256) void out_kernel(
    const float* __restrict__ Q, const float* __restrict__ S,
    const float* __restrict__ chunkOff, const float* __restrict__ TM,
    float* __restrict__ out)
{
    __shared__ float segEnd[4][64];
    const int w    = threadIdx.x >> 6;
    const int lane = threadIdx.x & 63;
    const int i    = blockIdx.x * 4 + w;

    segEnd[w][lane] = TM[w * T + lane * 64 + 63];
    const float t1i = TM[i];
    const float q0  = Q[(size_t)i * D + lane];
    const float q1  = (lane < 2) ? Q[(size_t)i * D + 64 + lane] : 0.0f;
    float acc0 = 0.0f, acc1 = 0.0f;
    __syncthreads();

    int seg[4];
#pragma unroll
    for (int mm = 0; mm < 4; ++mm) {
        const unsigned long long b = __ballot(segEnd[mm][lane] <= t1i);
        const int hi = __popcll(b);
        seg[mm] = (hi < 63) ? hi : 63;
    }
    int idx[4];
#pragma unroll
    for (int mm = 0; mm < 4; ++mm) {
        const float sv = TM[mm * T + seg[mm] * 64 + lane];
        const unsigned long long b = __ballot(sv <= t1i);
        idx[mm] = seg[mm] * 64 + __popcll(b) - 1;
    }

#pragma unroll
    for (int mm = 0; mm < 4; ++mm) {
        if (idx[mm] >= 0) {
            const float* sp = S + ((size_t)mm * T + idx[mm]) * 132;
            const float* op = chunkOff + ((size_t)mm * NC + (idx[mm] / JC)) * 132;
            const float2 s0 = *(const float2*)(sp + lane * 2);
            const float2 c0 = *(const float2*)(op + lane * 2);
            acc0 = fmaf(q0, s0.x + c0.x, acc0);
            acc1 = fmaf(q0, s0.y + c0.y, acc1);
            if (lane < 2) {
                const float2 s1 = *(const float2*)(sp + 128 + lane * 2);
                const float2 c1 = *(const float2*)(op + 128 + lane * 2);
                acc0 = fmaf(q1, s1.x + c1.x, acc0);
                acc1 = fmaf(q1, s1.y + c1.y, acc1);
            }
        }
    }

#pragma unroll
    for (int off = 32; off >= 1; off >>= 1) {
        acc0 += __shfl_down(acc0, off);
        acc1 += __shfl_down(acc1, off);
    }
    if (lane == 0) {
        out[(size_t)i * 2 + 0] = acc0;
        out[(size_t)i * 2 + 1] = acc1;
    }
}

extern "C" void kernel_launch(void* const* d_in, const int* in_sizes, int n_in,
                              void* d_out, int out_size, void* d_ws, size_t ws_size,
                              hipStream_t stream)
{
    (void)in_sizes; (void)n_in; (void)out_size; (void)ws_size;
    const float* x1 = (const float*)d_in[0];
    const float* x2 = (const float*)d_in[1];
    const float* x3 = (const float*)d_in[2];
    const float* x4 = (const float*)d_in[3];
    const float* wq = (const float*)d_in[4];
    const float* bq = (const float*)d_in[5];
    const float* wk = (const float*)d_in[6];
    const float* bk = (const float*)d_in[7];

    float* ws = (float*)d_ws;
    float* Q        = ws;                  // 4096*66            = 270336
    float* S        = ws + 270336;         // 4*4096*132         = 2162688
    float* chunkSum = ws + 2433024;        // 4*NC*132           = 33792
    float* chunkOff = ws + 2466816;        // 4*NC*132           = 33792
    float* TM       = ws + 2500608;        // 4*4096             = 16384
                                           // total ~10.07 MB

    mlp_scan_kernel<<<320, 256, 0, stream>>>(x1, x2, x3, x4, wq, bq, wk, bk,
                                             Q, S, chunkSum, TM);
    chunkscan_kernel<<<dim3(33, 4), 256, 0, stream>>>(chunkSum, chunkOff);
    out_kernel<<<1024, 256, 0, stream>>>(Q, S, chunkOff, TM, (float*)d_out);
}